// Round 9
// baseline (279.349 us; speedup 1.0000x reference)
//
#include <hip/hip_runtime.h>
#include <math.h>

#define Bz 8
#define NQ 4096
#define NKV 4096
#define Cc 256
#define KNN 16
#define Hh 32
#define EPSf 1e-5f
#define SLOPEf 0.2f

typedef unsigned long long u64t;

// ---- workspace layout (bytes) ----
#define OFF_W1AS 0u                       // 32*256 f32 (alpha1-folded w1a)
#define OFF_W1DS (OFF_W1AS + 32768u)      // 32*256 f32 (alpha1-folded (w1b-w1a))
#define OFF_W2T  (OFF_W1DS + 32768u)      // 32*256 f32 w2t[h][c] = alpha2[c]*w2[c][h]
#define OFF_C1   (OFF_W2T + 32768u)       // 32 f32: b1 - alpha1*m1
#define OFF_B2F  (OFF_C1 + 1024u)         // 256 f32: b2 - alpha2*m2
#define OFF_KVS  (OFF_B2F + 2048u)        // 8*4096*32 f32
#define OFF_QADD (OFF_KVS + 4194304u)     // 8*4096*32 f32
#define OFF_PD   (OFF_QADD + 4194304u)    // 8*4096*NSL*16 f64 per-slice sorted keys

__device__ __forceinline__ float leaky(float x) { return fmaxf(x, SLOPEf * x); }

// f64 comparators: CAS = v_min_f64 + v_max_f64 (2 instrs); MND = v_min_f64 (1)
#define CASD(A, B) { double lo_ = fmin(A, B); double hi_ = fmax(A, B); (A) = lo_; (B) = hi_; }
#define MND(A, B)  { (A) = fmin(A, B); }

// Batcher odd-even mergesort, 16 elements, 63 comparators (c0..c15 ascending)
#define SORTC16 \
  CASD(c0,c1) CASD(c2,c3) CASD(c4,c5) CASD(c6,c7) CASD(c8,c9) CASD(c10,c11) CASD(c12,c13) CASD(c14,c15) \
  CASD(c0,c2) CASD(c4,c6) CASD(c8,c10) CASD(c12,c14) CASD(c1,c3) CASD(c5,c7) CASD(c9,c11) CASD(c13,c15) \
  CASD(c1,c2) CASD(c5,c6) CASD(c9,c10) CASD(c13,c14) \
  CASD(c0,c4) CASD(c8,c12) CASD(c1,c5) CASD(c9,c13) CASD(c2,c6) CASD(c10,c14) CASD(c3,c7) CASD(c11,c15) \
  CASD(c2,c4) CASD(c10,c12) CASD(c3,c5) CASD(c11,c13) \
  CASD(c1,c2) CASD(c3,c4) CASD(c5,c6) CASD(c9,c10) CASD(c11,c12) CASD(c13,c14) \
  CASD(c0,c8) CASD(c1,c9) CASD(c2,c10) CASD(c3,c11) CASD(c4,c12) CASD(c5,c13) CASD(c6,c14) CASD(c7,c15) \
  CASD(c4,c8) CASD(c5,c9) CASD(c6,c10) CASD(c7,c11) \
  CASD(c2,c4) CASD(c3,c5) CASD(c6,c8) CASD(c7,c9) CASD(c10,c12) CASD(c11,c13) \
  CASD(c1,c2) CASD(c3,c4) CASD(c5,c6) CASD(c7,c8) CASD(c9,c10) CASD(c11,c12) CASD(c13,c14)

// keep-lowest-16 of sorted b (asc) U sorted c (asc): reversed pairwise min, bitonic clean
#define MERGE16 \
  MND(b0,c15) MND(b1,c14) MND(b2,c13) MND(b3,c12) MND(b4,c11) MND(b5,c10) MND(b6,c9) MND(b7,c8) \
  MND(b8,c7) MND(b9,c6) MND(b10,c5) MND(b11,c4) MND(b12,c3) MND(b13,c2) MND(b14,c1) MND(b15,c0) \
  CASD(b0,b8) CASD(b1,b9) CASD(b2,b10) CASD(b3,b11) CASD(b4,b12) CASD(b5,b13) CASD(b6,b14) CASD(b7,b15) \
  CASD(b0,b4) CASD(b1,b5) CASD(b2,b6) CASD(b3,b7) CASD(b8,b12) CASD(b9,b13) CASD(b10,b14) CASD(b11,b15) \
  CASD(b0,b2) CASD(b1,b3) CASD(b4,b6) CASD(b5,b7) CASD(b8,b10) CASD(b9,b11) CASD(b12,b14) CASD(b13,b15) \
  CASD(b0,b1) CASD(b2,b3) CASD(b4,b5) CASD(b6,b7) CASD(b8,b9) CASD(b10,b11) CASD(b12,b13) CASD(b14,b15)

#define LOADB16(P) \
  b0 = (P)[0]; b1 = (P)[1]; b2 = (P)[2]; b3 = (P)[3]; b4 = (P)[4]; b5 = (P)[5]; b6 = (P)[6]; b7 = (P)[7]; \
  b8 = (P)[8]; b9 = (P)[9]; b10 = (P)[10]; b11 = (P)[11]; b12 = (P)[12]; b13 = (P)[13]; b14 = (P)[14]; b15 = (P)[15];
#define LOADC16(P) \
  c0 = (P)[0]; c1 = (P)[1]; c2 = (P)[2]; c3 = (P)[3]; c4 = (P)[4]; c5 = (P)[5]; c6 = (P)[6]; c7 = (P)[7]; \
  c8 = (P)[8]; c9 = (P)[9]; c10 = (P)[10]; c11 = (P)[11]; c12 = (P)[12]; c13 = (P)[13]; c14 = (P)[14]; c15 = (P)[15];
#define STOREB16(P) \
  (P)[0] = b0; (P)[1] = b1; (P)[2] = b2; (P)[3] = b3; (P)[4] = b4; (P)[5] = b5; (P)[6] = b6; (P)[7] = b7; \
  (P)[8] = b8; (P)[9] = b9; (P)[10] = b10; (P)[11] = b11; (P)[12] = b12; (P)[13] = b13; (P)[14] = b14; (P)[15] = b15;

// ------- kernel 1: weight-fold (piggyback, blocks 0..64) + SELF-PACKING per-slice top-16 -------
// [r7/r8-verified, absmax canary held] sel key = bits((double)dist_f32) | idx ; dist >= 1
// (|q|^2+1 bias) => positive f64, value order == bit order == (f32 dist, idx) lex ==
// jax top_k semantics. Ledger: r1 block-fusion regressed (I$/LDS); r2 NSL=16 regressed
// (2x pd traffic); r6 grid barrier HUNG; r7 qadd-in-tail +115us (no slack at low TLP).
template <int SLt>
__global__ __launch_bounds__(256) void k_selp(
    const float* __restrict__ qxyz, const float* __restrict__ kxyz,
    const float* __restrict__ w1p, const float* __restrict__ g1p,
    const float* __restrict__ b1p, const float* __restrict__ m1p,
    const float* __restrict__ v1p, const float* __restrict__ w2p,
    const float* __restrict__ g2p, const float* __restrict__ b2p,
    const float* __restrict__ m2p, const float* __restrict__ v2p,
    char* __restrict__ ws, double* __restrict__ pd) {
  constexpr int NSLt = NKV / SLt;
  __shared__ float4 lk[SLt];
  int t = threadIdx.x;
  int blk = blockIdx.x;

  // ---- piggybacked weight fold (touches 65 of the blocks, ~2 extra mem ops each) ----
  if (blk < 32) {
    int i = blk * 256 + t;  // i = h*256 + c
    int h = i >> 8, c = i & 255;
    float a1 = g1p[h] / sqrtf(v1p[h] + EPSf);
    float wa = w1p[h * 2 * Cc + c];
    float wb = w1p[h * 2 * Cc + Cc + c];
    ((float*)(ws + OFF_W1AS))[i] = a1 * wa;
    ((float*)(ws + OFF_W1DS))[i] = a1 * (wb - wa);
  } else if (blk < 64) {
    int j = (blk - 32) * 256 + t;  // j = c*32 + h (w2 linear -> coalesced read)
    int c = j >> 5, h = j & 31;
    float a2 = g2p[c] / sqrtf(v2p[c] + EPSf);
    ((float*)(ws + OFF_W2T))[h * Cc + c] = a2 * w2p[j];
  } else if (blk == 64) {
    if (t < Hh) {
      float a1 = g1p[t] / sqrtf(v1p[t] + EPSf);
      ((float*)(ws + OFF_C1))[t] = b1p[t] - a1 * m1p[t];
    }
    if (t < Cc) {
      float a2 = g2p[t] / sqrtf(v2p[t] + EPSf);
      ((float*)(ws + OFF_B2F))[t] = b2p[t] - a2 * m2p[t];
    }
  }

  // ---- sel (self-packing: stages SLt keys straight from kxyz; prep kernel deleted) ----
  int qt = blk & 15;
  int s = (blk >> 4) % NSLt;
  int b = blk / (16 * NSLt);
  int kb = b * NKV + s * SLt;
#pragma unroll
  for (int i = 0; i < SLt / 256; ++i) {
    int j = i * 256 + t;
    const float* src = kxyz + (size_t)(kb + j) * 3;
    float4 v; v.x = src[0]; v.y = src[1]; v.z = src[2];
    v.w = fmaf(v.x, v.x, fmaf(v.y, v.y, v.z * v.z));
    lk[j] = v;
  }
  int q = qt * 256 + t;
  const float* qsrc = qxyz + (size_t)(b * NQ + q) * 3;
  float qxv = qsrc[0], qyv = qsrc[1], qzv = qsrc[2];
  float qw = fmaf(qxv, qxv, fmaf(qyv, qyv, qzv * qzv)) + 1.0f;
  float qx2 = -2.0f * qxv, qy2 = -2.0f * qyv, qz2 = -2.0f * qzv;
  __syncthreads();
  int gbase = s * SLt;
  double b0, b1, b2, b3, b4, b5, b6, b7, b8, b9, b10, b11, b12, b13, b14, b15;
#define MK(J) { float4 kv = lk[o + J]; \
  float dq = fmaf(qx2, kv.x, fmaf(qy2, kv.y, fmaf(qz2, kv.z, kv.w + qw))); \
  c##J = __longlong_as_double(__double_as_longlong((double)dq) | (long long)(ib + J)); }
  {  // first 16 keys: sort straight into b (no sentinel merge)
    int o = 0, ib = gbase;
    double c0, c1, c2, c3, c4, c5, c6, c7, c8, c9, c10, c11, c12, c13, c14, c15;
    MK(0) MK(1) MK(2) MK(3) MK(4) MK(5) MK(6) MK(7)
    MK(8) MK(9) MK(10) MK(11) MK(12) MK(13) MK(14) MK(15)
    SORTC16
    b0 = c0; b1 = c1; b2 = c2; b3 = c3; b4 = c4; b5 = c5; b6 = c6; b7 = c7;
    b8 = c8; b9 = c9; b10 = c10; b11 = c11; b12 = c12; b13 = c13; b14 = c14; b15 = c15;
  }
#pragma unroll 4
  for (int blki = 1; blki < SLt / 16; ++blki) {
    int o = blki * 16;
    int ib = gbase + o;
    double c0, c1, c2, c3, c4, c5, c6, c7, c8, c9, c10, c11, c12, c13, c14, c15;
    MK(0) MK(1) MK(2) MK(3) MK(4) MK(5) MK(6) MK(7)
    MK(8) MK(9) MK(10) MK(11) MK(12) MK(13) MK(14) MK(15)
    SORTC16
    MERGE16
  }
#undef MK
  double* ob = pd + (((size_t)b * NQ + q) * NSLt + s) * KNN;
  ob[0] = b0; ob[1] = b1; ob[2] = b2; ob[3] = b3;
  ob[4] = b4; ob[5] = b5; ob[6] = b6; ob[7] = b7;
  ob[8] = b8; ob[9] = b9; ob[10] = b10; ob[11] = b11;
  ob[12] = b12; ob[13] = b13; ob[14] = b14; ob[15] = b15;
}

// ------------- kernel 2: kvs = (a1*w1a)·kv_feat ; qadd = (a1*w1d)·q_feat + c1 -------------
// [r4/r8-verified] 128-row tiles, acc[4h][4r]; fma chain order per output element identical
// to the r0 body (bit-exact).
__global__ __launch_bounds__(256) void k_feat(
    const float* __restrict__ kvf, const float* __restrict__ qf,
    const char* __restrict__ ws_c, char* __restrict__ ws_o) {
  __shared__ __align__(16) float fs[128][68];   // 34.8 KB
  __shared__ __align__(16) float wsh[32][68];   // 8.7 KB
  int t = threadIdx.x;
  int hh = t & 7, rr = t >> 3;                  // hh 0..7, rr 0..31
  int b = blockIdx.y, m0 = blockIdx.x * 128, mode = blockIdx.z;
  const float* in = mode ? qf : kvf;
  const float* w = (const float*)(ws_c + (mode ? OFF_W1DS : OFF_W1AS));
  const float* c1 = (const float*)(ws_c + OFF_C1);
  float* out = (float*)(ws_o + (mode ? OFF_QADD : OFF_KVS));
  const float* inb = in + ((size_t)b * NKV + m0) * Cc;
  float acc[4][4];
#pragma unroll
  for (int i = 0; i < 4; ++i)
#pragma unroll
    for (int j = 0; j < 4; ++j) acc[i][j] = 0.f;
  for (int cc = 0; cc < 4; ++cc) {
    __syncthreads();
#pragma unroll
    for (int i = 0; i < 8; ++i) {  // stage 128x64 feat tile
      int l = i * 256 + t, row = l >> 4, c4 = l & 15;
      *(float4*)&fs[row][c4 * 4] = *(const float4*)(inb + (size_t)row * Cc + cc * 64 + c4 * 4);
    }
#pragma unroll
    for (int i = 0; i < 2; ++i) {  // stage 32x64 weight tile
      int l = i * 256 + t, row = l >> 4, c4 = l & 15;
      *(float4*)&wsh[row][c4 * 4] = *(const float4*)(w + (size_t)row * Cc + cc * 64 + c4 * 4);
    }
    __syncthreads();
#pragma unroll
    for (int c4 = 0; c4 < 16; ++c4) {
      float4 wv[4], fv[4];
#pragma unroll
      for (int i = 0; i < 4; ++i) wv[i] = *(float4*)&wsh[hh + i * 8][c4 * 4];
#pragma unroll
      for (int j = 0; j < 4; ++j) fv[j] = *(float4*)&fs[rr + j * 32][c4 * 4];
#pragma unroll
      for (int i = 0; i < 4; ++i)
#pragma unroll
        for (int j = 0; j < 4; ++j)
          acc[i][j] = fmaf(wv[i].x, fv[j].x, fmaf(wv[i].y, fv[j].y,
                      fmaf(wv[i].z, fv[j].z, fmaf(wv[i].w, fv[j].w, acc[i][j]))));
    }
  }
  float* ob = out + ((size_t)b * NKV + m0) * Hh;
#pragma unroll
  for (int i = 0; i < 4; ++i) {
    float add = mode ? c1[hh + i * 8] : 0.f;
#pragma unroll
    for (int j = 0; j < 4; ++j)
      ob[(size_t)(rr + j * 32) * Hh + hh + i * 8] = acc[i][j] + add;
  }
}

// ------------- kernel 3 (fused tail): merge tree -> gather+maxpool -> matvec+BN2+leaky -------------
// r9: 16 q/block, grid 2048. r7 profile showed tail latency-bound (VALUBusy 11.6%, HBM 7.6%,
// occupancy 36% at 4 blocks/CU) — the pd read (33.5 MB, L2-cold, ~900cy) is drained with too
// little MLP. Halving the block (LDS 32.5 -> 16.4 KB) roughly doubles co-resident blocks/CU.
// Merge pairs/order, gather, and phase-3 fma chain order identical to r8 -> bit-exact.
// Phase 3 reads xs per-h from LDS (broadcast, conflict-free) instead of xv[32] preload to
// keep VGPR <= ~64 for occupancy.
template <int NSLt>
__global__ __launch_bounds__(256, 6) void k_tail(
    const double* __restrict__ pd, const char* __restrict__ ws_c,
    float* __restrict__ out) {
  __shared__ double mg[16][NSLt / 2][17];                 // 8.7 KB (NSL=8)
  __shared__ double mg2[(NSLt == 8) ? 16 : 1][2][17];     // 4.35 KB
  __shared__ int sidx[16 * 17];                           // 1.1 KB
  __shared__ float xs[Hh * 17];                           // 2.2 KB, xs[h][q] stride 17
  int t = threadIdx.x;
  int b = blockIdx.y, q0 = blockIdx.x * 16;

  // hoisted phase-2 operand (independent of phase 1); only t<128 participates in phase 2
  int q2 = t >> 3, l2 = t & 7;
  float4 av = make_float4(0.f, 0.f, 0.f, 0.f);
  if (t < 128) {
    const float4* qa = (const float4*)(ws_c + OFF_QADD) + ((size_t)b * NQ + q0 + q2) * 8 + l2;
    av = *qa;
  }

  const double* base = pd + ((size_t)b * NQ + q0) * NSLt * KNN;
  double b0, b1, b2, b3, b4, b5, b6, b7, b8, b9, b10, b11, b12, b13, b14, b15;
  double c0, c1, c2, c3, c4, c5, c6, c7, c8, c9, c10, c11, c12, c13, c14, c15;

  if constexpr (NSLt == 8) {
    if (t < 64) {  // level 1: 4 thr/q, thread p merges lists (2p, 2p+1) — contiguous 256 B
      int q = t >> 2, p = t & 3;
      const double* L = base + ((size_t)q * NSLt + 2 * p) * KNN;
      LOADB16(L)
      LOADC16(L + 16)
      MERGE16
      STOREB16(&mg[q][p][0])
    }
    __syncthreads();
    if (t < 32) {  // level 2
      int q = t >> 1, p = t & 1;
      LOADB16(&mg[q][2 * p][0])
      LOADC16(&mg[q][2 * p + 1][0])
      MERGE16
      STOREB16(&mg2[q][p][0])
    }
    __syncthreads();
  } else {  // NSLt == 4
    if (t < 32) {
      int q = t >> 1, p = t & 1;
      const double* L = base + ((size_t)q * NSLt + 2 * p) * KNN;
      LOADB16(L)
      LOADC16(L + 16)
      MERGE16
      STOREB16(&mg[q][p][0])
    }
    __syncthreads();
  }
  if (t < 16) {  // final level -> sidx (OR-packed keys: idx = low 12 mantissa bits)
    if constexpr (NSLt == 8) {
      LOADB16(&mg2[t][0][0])
      LOADC16(&mg2[t][1][0])
    } else {
      LOADB16(&mg[t][0][0])
      LOADC16(&mg[t][1][0])
    }
    MERGE16
    int* si = &sidx[t * 17];
    si[0] = (int)(__double_as_longlong(b0) & 4095);
    si[1] = (int)(__double_as_longlong(b1) & 4095);
    si[2] = (int)(__double_as_longlong(b2) & 4095);
    si[3] = (int)(__double_as_longlong(b3) & 4095);
    si[4] = (int)(__double_as_longlong(b4) & 4095);
    si[5] = (int)(__double_as_longlong(b5) & 4095);
    si[6] = (int)(__double_as_longlong(b6) & 4095);
    si[7] = (int)(__double_as_longlong(b7) & 4095);
    si[8] = (int)(__double_as_longlong(b8) & 4095);
    si[9] = (int)(__double_as_longlong(b9) & 4095);
    si[10] = (int)(__double_as_longlong(b10) & 4095);
    si[11] = (int)(__double_as_longlong(b11) & 4095);
    si[12] = (int)(__double_as_longlong(b12) & 4095);
    si[13] = (int)(__double_as_longlong(b13) & 4095);
    si[14] = (int)(__double_as_longlong(b14) & 4095);
    si[15] = (int)(__double_as_longlong(b15) & 4095);
  }
  __syncthreads();
  // ---- phase 2: gather + maxpool + qadd + leaky -> xs (transposed, stride 17) ----
  if (t < 128) {
    const float4* kvs = (const float4*)(ws_c + OFF_KVS) + (size_t)b * NKV * 8 + l2;
    float4 p0 = make_float4(-3.4e38f, -3.4e38f, -3.4e38f, -3.4e38f);
#pragma unroll
    for (int n = 0; n < KNN; ++n) {
      int m = sidx[q2 * 17 + n];
      float4 v0 = kvs[(size_t)m * 8];
      p0.x = fmaxf(p0.x, v0.x); p0.y = fmaxf(p0.y, v0.y);
      p0.z = fmaxf(p0.z, v0.z); p0.w = fmaxf(p0.w, v0.w);
    }
    int h0 = 4 * l2;
    xs[(h0 + 0) * 17 + q2] = leaky(p0.x + av.x);
    xs[(h0 + 1) * 17 + q2] = leaky(p0.y + av.y);
    xs[(h0 + 2) * 17 + q2] = leaky(p0.z + av.z);
    xs[(h0 + 3) * 17 + q2] = leaky(p0.w + av.w);
  }
  __syncthreads();
  // ---- phase 3: y = leaky(w2t · x + b2f) ----  (16 q x 16 col-blocks of 16)
  {
    int ql = t & 15, cb = t >> 4;  // cb 0..15, 16 cols each
    const float* w2t = (const float*)(ws_c + OFF_W2T);
    const float* b2f = (const float*)(ws_c + OFF_B2F);
    float4 acc[4];
#pragma unroll
    for (int c4 = 0; c4 < 4; ++c4) acc[c4] = make_float4(0.f, 0.f, 0.f, 0.f);
#pragma unroll
    for (int h = 0; h < Hh; ++h) {
      float xh = xs[h * 17 + ql];  // broadcast within 16-lane groups, conflict-free
      const float4* wrow = (const float4*)(w2t + (size_t)h * Cc + cb * 16);
#pragma unroll
      for (int c4 = 0; c4 < 4; ++c4) {
        float4 w = wrow[c4];
        acc[c4].x = fmaf(xh, w.x, acc[c4].x);
        acc[c4].y = fmaf(xh, w.y, acc[c4].y);
        acc[c4].z = fmaf(xh, w.z, acc[c4].z);
        acc[c4].w = fmaf(xh, w.w, acc[c4].w);
      }
    }
    float* o = out + ((size_t)b * NQ + q0 + ql) * Cc + cb * 16;
    const float4* bb = (const float4*)(b2f + cb * 16);
#pragma unroll
    for (int c4 = 0; c4 < 4; ++c4) {
      float4 bv = bb[c4];
      float4 r;
      r.x = leaky(acc[c4].x + bv.x); r.y = leaky(acc[c4].y + bv.y);
      r.z = leaky(acc[c4].z + bv.z); r.w = leaky(acc[c4].w + bv.w);
      *(float4*)(o + c4 * 4) = r;
    }
  }
}

extern "C" void kernel_launch(void* const* d_in, const int* in_sizes, int n_in,
                              void* d_out, int out_size, void* d_ws, size_t ws_size,
                              hipStream_t stream) {
  const float* qf   = (const float*)d_in[0];
  const float* qxyz = (const float*)d_in[1];
  const float* kvf  = (const float*)d_in[2];
  const float* kxyz = (const float*)d_in[3];
  const float* w1 = (const float*)d_in[4];
  const float* g1 = (const float*)d_in[5];
  const float* b1 = (const float*)d_in[6];
  const float* m1 = (const float*)d_in[7];
  const float* v1 = (const float*)d_in[8];
  const float* w2 = (const float*)d_in[9];
  const float* g2 = (const float*)d_in[10];
  const float* b2 = (const float*)d_in[11];
  const float* m2 = (const float*)d_in[12];
  const float* v2 = (const float*)d_in[13];
  char* ws = (char*)d_ws;
  double* pd = (double*)(ws + OFF_PD);

  // NSL=8 needs OFF_PD + 8*4096*8*16*8 ~= 42 MB of ws; fall back to NSL=4 otherwise.
  size_t need8 = (size_t)OFF_PD + (size_t)Bz * NQ * 8 * KNN * sizeof(double);
  if (ws_size >= need8) {
    k_selp<512><<<dim3(1024), dim3(256), 0, stream>>>(
        qxyz, kxyz, w1, g1, b1, m1, v1, w2, g2, b2, m2, v2, ws, pd);
    k_feat<<<dim3(NKV / 128, Bz, 2), 256, 0, stream>>>(kvf, qf, ws, ws);
    k_tail<8><<<dim3(NQ / 16, Bz), 256, 0, stream>>>(pd, ws, (float*)d_out);
  } else {
    k_selp<1024><<<dim3(512), dim3(256), 0, stream>>>(
        qxyz, kxyz, w1, g1, b1, m1, v1, w2, g2, b2, m2, v2, ws, pd);
    k_feat<<<dim3(NKV / 128, Bz, 2), 256, 0, stream>>>(kvf, qf, ws, ws);
    k_tail<4><<<dim3(NQ / 16, Bz), 256, 0, stream>>>(pd, ws, (float*)d_out);
  }
}

// Round 10
// 252.883 us; speedup vs baseline: 1.1047x; 1.1047x over previous
//
#include <hip/hip_runtime.h>
#include <math.h>

#define Bz 8
#define NQ 4096
#define NKV 4096
#define Cc 256
#define KNN 16
#define Hh 32
#define EPSf 1e-5f
#define SLOPEf 0.2f

typedef unsigned long long u64t;

// ---- workspace layout (bytes) ----
#define OFF_W2T  0u                       // 32*256 f32 w2t[h][c] = alpha2[c]*w2[c][h]
#define OFF_B2F  (OFF_W2T + 32768u)       // 256 f32: b2 - alpha2*m2
#define OFF_KVS  (OFF_B2F + 2048u)        // 8*4096*32 f32
#define OFF_QADD (OFF_KVS + 4194304u)     // 8*4096*32 f32
#define OFF_PD   (OFF_QADD + 4194304u)    // 8*4096*NSL*16 f64 per-slice sorted keys

__device__ __forceinline__ float leaky(float x) { return fmaxf(x, SLOPEf * x); }

// f64 comparators: CAS = v_min_f64 + v_max_f64 (2 instrs); MND = v_min_f64 (1)
#define CASD(A, B) { double lo_ = fmin(A, B); double hi_ = fmax(A, B); (A) = lo_; (B) = hi_; }
#define MND(A, B)  { (A) = fmin(A, B); }

// Batcher odd-even mergesort, 16 elements, 63 comparators (c0..c15 ascending)
#define SORTC16 \
  CASD(c0,c1) CASD(c2,c3) CASD(c4,c5) CASD(c6,c7) CASD(c8,c9) CASD(c10,c11) CASD(c12,c13) CASD(c14,c15) \
  CASD(c0,c2) CASD(c4,c6) CASD(c8,c10) CASD(c12,c14) CASD(c1,c3) CASD(c5,c7) CASD(c9,c11) CASD(c13,c15) \
  CASD(c1,c2) CASD(c5,c6) CASD(c9,c10) CASD(c13,c14) \
  CASD(c0,c4) CASD(c8,c12) CASD(c1,c5) CASD(c9,c13) CASD(c2,c6) CASD(c10,c14) CASD(c3,c7) CASD(c11,c15) \
  CASD(c2,c4) CASD(c10,c12) CASD(c3,c5) CASD(c11,c13) \
  CASD(c1,c2) CASD(c3,c4) CASD(c5,c6) CASD(c9,c10) CASD(c11,c12) CASD(c13,c14) \
  CASD(c0,c8) CASD(c1,c9) CASD(c2,c10) CASD(c3,c11) CASD(c4,c12) CASD(c5,c13) CASD(c6,c14) CASD(c7,c15) \
  CASD(c4,c8) CASD(c5,c9) CASD(c6,c10) CASD(c7,c11) \
  CASD(c2,c4) CASD(c3,c5) CASD(c6,c8) CASD(c7,c9) CASD(c10,c12) CASD(c11,c13) \
  CASD(c1,c2) CASD(c3,c4) CASD(c5,c6) CASD(c7,c8) CASD(c9,c10) CASD(c11,c12) CASD(c13,c14)

// keep-lowest-16 of sorted b (asc) U sorted c (asc): reversed pairwise min, bitonic clean
#define MERGE16 \
  MND(b0,c15) MND(b1,c14) MND(b2,c13) MND(b3,c12) MND(b4,c11) MND(b5,c10) MND(b6,c9) MND(b7,c8) \
  MND(b8,c7) MND(b9,c6) MND(b10,c5) MND(b11,c4) MND(b12,c3) MND(b13,c2) MND(b14,c1) MND(b15,c0) \
  CASD(b0,b8) CASD(b1,b9) CASD(b2,b10) CASD(b3,b11) CASD(b4,b12) CASD(b5,b13) CASD(b6,b14) CASD(b7,b15) \
  CASD(b0,b4) CASD(b1,b5) CASD(b2,b6) CASD(b3,b7) CASD(b8,b12) CASD(b9,b13) CASD(b10,b14) CASD(b11,b15) \
  CASD(b0,b2) CASD(b1,b3) CASD(b4,b6) CASD(b5,b7) CASD(b8,b10) CASD(b9,b11) CASD(b12,b14) CASD(b13,b15) \
  CASD(b0,b1) CASD(b2,b3) CASD(b4,b5) CASD(b6,b7) CASD(b8,b9) CASD(b10,b11) CASD(b12,b13) CASD(b14,b15)

#define LOADB16(P) \
  b0 = (P)[0]; b1 = (P)[1]; b2 = (P)[2]; b3 = (P)[3]; b4 = (P)[4]; b5 = (P)[5]; b6 = (P)[6]; b7 = (P)[7]; \
  b8 = (P)[8]; b9 = (P)[9]; b10 = (P)[10]; b11 = (P)[11]; b12 = (P)[12]; b13 = (P)[13]; b14 = (P)[14]; b15 = (P)[15];
#define LOADC16(P) \
  c0 = (P)[0]; c1 = (P)[1]; c2 = (P)[2]; c3 = (P)[3]; c4 = (P)[4]; c5 = (P)[5]; c6 = (P)[6]; c7 = (P)[7]; \
  c8 = (P)[8]; c9 = (P)[9]; c10 = (P)[10]; c11 = (P)[11]; c12 = (P)[12]; c13 = (P)[13]; c14 = (P)[14]; c15 = (P)[15];
#define STOREB16(P) \
  (P)[0] = b0; (P)[1] = b1; (P)[2] = b2; (P)[3] = b3; (P)[4] = b4; (P)[5] = b5; (P)[6] = b6; (P)[7] = b7; \
  (P)[8] = b8; (P)[9] = b9; (P)[10] = b10; (P)[11] = b11; (P)[12] = b12; (P)[13] = b13; (P)[14] = b14; (P)[15] = b15;

// ======= kernel 1: sel phase -> feat phase (sequential, NO grid barrier needed) =======
// feat is INDEPENDENT of sel's output; blocks roll from sel straight into feat, removing
// the sel drain + one dispatch gap. a1/c1 folded IN-BLOCK for feat (same fp expressions as
// the old prep -> bit-identical); w2t/b2f fold (consumed by k_tail next dispatch) stays
// piggybacked on blocks 0..32.
// sel key = bits((double)dist_f32) | idx ; dist >= 1 (|q|^2+1 bias) => positive f64 =>
// value order == bit order == (f32 dist, idx) lex == jax top_k tie semantics.
// Ledger: r1 CONCURRENT block-fusion regressed (full-duration I$/LDS mix — this version is
// phase-sequential, mixed-code only in the transition window); r2 NSL=16 regressed (2x pd
// traffic); r6 grid barrier HUNG; r7 qadd-in-tail +115us; r9 tail halving neutral (3rd
// neutral tail restructure -> tail is pd-round-trip-bound, stop touching it).
template <int SLt>
__global__ __launch_bounds__(256) void k_sf(
    const float* __restrict__ qxyz, const float* __restrict__ kxyz,
    const float* __restrict__ kvf, const float* __restrict__ qf,
    const float* __restrict__ w1p, const float* __restrict__ g1p,
    const float* __restrict__ b1p, const float* __restrict__ m1p,
    const float* __restrict__ v1p, const float* __restrict__ w2p,
    const float* __restrict__ g2p, const float* __restrict__ b2p,
    const float* __restrict__ m2p, const float* __restrict__ v2p,
    char* __restrict__ ws, double* __restrict__ pd) {
  constexpr int NSLt = NKV / SLt;
  constexpr int SELU = 16 * NSLt * Bz;          // 1024 (NSL=8) / 512 (NSL=4)
  __shared__ __align__(16) char smem[26368];    // sel lk (8/16K) then feat fs+wsh (26.1K) + a1s/c1s
  int t = threadIdx.x;
  int blk = blockIdx.x;

  // ---- piggybacked fold of tail-side constants (w2t, b2f) ----
  if (blk < 32) {
    int j = blk * 256 + t;  // j = c*32 + h (w2 linear -> coalesced read)
    int c = j >> 5, h = j & 31;
    float a2 = g2p[c] / sqrtf(v2p[c] + EPSf);
    ((float*)(ws + OFF_W2T))[h * Cc + c] = a2 * w2p[j];
  } else if (blk == 32) {
    if (t < Cc) {
      float a2 = g2p[t] / sqrtf(v2p[t] + EPSf);
      ((float*)(ws + OFF_B2F))[t] = b2p[t] - a2 * m2p[t];
    }
  }

  // ================= phase A: self-packing per-slice top-16 =================
  if (blk < SELU) {
    float4* lk = (float4*)smem;
    int qt = blk & 15;
    int s = (blk >> 4) % NSLt;
    int b = blk / (16 * NSLt);
    int kb = b * NKV + s * SLt;
#pragma unroll
    for (int i = 0; i < SLt / 256; ++i) {
      int j = i * 256 + t;
      const float* src = kxyz + (size_t)(kb + j) * 3;
      float4 v; v.x = src[0]; v.y = src[1]; v.z = src[2];
      v.w = fmaf(v.x, v.x, fmaf(v.y, v.y, v.z * v.z));
      lk[j] = v;
    }
    int q = qt * 256 + t;
    const float* qsrc = qxyz + (size_t)(b * NQ + q) * 3;
    float qxv = qsrc[0], qyv = qsrc[1], qzv = qsrc[2];
    float qw = fmaf(qxv, qxv, fmaf(qyv, qyv, qzv * qzv)) + 1.0f;
    float qx2 = -2.0f * qxv, qy2 = -2.0f * qyv, qz2 = -2.0f * qzv;
    __syncthreads();
    int gbase = s * SLt;
    double b0, b1, b2, b3, b4, b5, b6, b7, b8, b9, b10, b11, b12, b13, b14, b15;
#define MK(J) { float4 kv = lk[o + J]; \
  float dq = fmaf(qx2, kv.x, fmaf(qy2, kv.y, fmaf(qz2, kv.z, kv.w + qw))); \
  c##J = __longlong_as_double(__double_as_longlong((double)dq) | (long long)(ib + J)); }
    {  // first 16 keys: sort straight into b (no sentinel merge)
      int o = 0, ib = gbase;
      double c0, c1, c2, c3, c4, c5, c6, c7, c8, c9, c10, c11, c12, c13, c14, c15;
      MK(0) MK(1) MK(2) MK(3) MK(4) MK(5) MK(6) MK(7)
      MK(8) MK(9) MK(10) MK(11) MK(12) MK(13) MK(14) MK(15)
      SORTC16
      b0 = c0; b1 = c1; b2 = c2; b3 = c3; b4 = c4; b5 = c5; b6 = c6; b7 = c7;
      b8 = c8; b9 = c9; b10 = c10; b11 = c11; b12 = c12; b13 = c13; b14 = c14; b15 = c15;
    }
#pragma unroll 4
    for (int blki = 1; blki < SLt / 16; ++blki) {
      int o = blki * 16;
      int ib = gbase + o;
      double c0, c1, c2, c3, c4, c5, c6, c7, c8, c9, c10, c11, c12, c13, c14, c15;
      MK(0) MK(1) MK(2) MK(3) MK(4) MK(5) MK(6) MK(7)
      MK(8) MK(9) MK(10) MK(11) MK(12) MK(13) MK(14) MK(15)
      SORTC16
      MERGE16
    }
#undef MK
    double* ob = pd + (((size_t)b * NQ + q) * NSLt + s) * KNN;
    ob[0] = b0; ob[1] = b1; ob[2] = b2; ob[3] = b3;
    ob[4] = b4; ob[5] = b5; ob[6] = b6; ob[7] = b7;
    ob[8] = b8; ob[9] = b9; ob[10] = b10; ob[11] = b11;
    ob[12] = b12; ob[13] = b13; ob[14] = b14; ob[15] = b15;
  }

  // ================= phase B: feat GEMMs (r0-verified 64-row body, inline a1/c1 fold) ====
  {
    float (*fs)[68]  = (float(*)[68])smem;            // 0 .. 17407
    float (*wsh)[68] = (float(*)[68])(smem + 17408);  // 17408 .. 26111
    float* a1s = (float*)(smem + 26112);              // 32 f32 (no alias with lk/fs/wsh)
    float* c1s = a1s + 32;                            // 32 f32
    if (t < Hh) {
      float a1 = g1p[t] / sqrtf(v1p[t] + EPSf);
      a1s[t] = a1;
      c1s[t] = b1p[t] - a1 * m1p[t];
    }
    int hh = t & 15, rr = t >> 4;
    int xb = blk & 63, b = (blk >> 6) & 7, mode = blk >> 9;  // 1024 units = 1:1 with grid
    int m0 = xb * 64;
    const float* in = mode ? qf : kvf;
    float* outw = (float*)(ws + (mode ? OFF_QADD : OFF_KVS));
    const float* inb = in + ((size_t)b * NKV + m0) * Cc;
    float acc[2][4] = {{0.f, 0.f, 0.f, 0.f}, {0.f, 0.f, 0.f, 0.f}};
    for (int cc = 0; cc < 4; ++cc) {
      __syncthreads();  // first iteration: also fences sel-phase lk reads + a1s/c1s writes
#pragma unroll
      for (int i = 0; i < 4; ++i) {  // stage 64x64 feat tile
        int l = i * 256 + t, row = l >> 4, c4 = l & 15;
        *(float4*)&fs[row][c4 * 4] = *(const float4*)(inb + (size_t)row * Cc + cc * 64 + c4 * 4);
      }
#pragma unroll
      for (int i = 0; i < 2; ++i) {  // stage 32x64 weight tile, folding a1 inline (bit-identical)
        int l = i * 256 + t, row = l >> 4, c4 = l & 15;
        float4 wa = *(const float4*)(w1p + (size_t)row * 2 * Cc + cc * 64 + c4 * 4);
        float a1 = a1s[row];
        float4 val;
        if (mode) {
          float4 wb = *(const float4*)(w1p + (size_t)row * 2 * Cc + Cc + cc * 64 + c4 * 4);
          val.x = a1 * (wb.x - wa.x); val.y = a1 * (wb.y - wa.y);
          val.z = a1 * (wb.z - wa.z); val.w = a1 * (wb.w - wa.w);
        } else {
          val.x = a1 * wa.x; val.y = a1 * wa.y; val.z = a1 * wa.z; val.w = a1 * wa.w;
        }
        *(float4*)&wsh[row][c4 * 4] = val;
      }
      __syncthreads();
#pragma unroll
      for (int c4 = 0; c4 < 16; ++c4) {
        float4 w0 = *(float4*)&wsh[hh][c4 * 4];
        float4 w1v = *(float4*)&wsh[hh + 16][c4 * 4];
#pragma unroll
        for (int j = 0; j < 4; ++j) {
          float4 f = *(float4*)&fs[rr + j * 16][c4 * 4];
          acc[0][j] = fmaf(w0.x, f.x, fmaf(w0.y, f.y, fmaf(w0.z, f.z, fmaf(w0.w, f.w, acc[0][j]))));
          acc[1][j] = fmaf(w1v.x, f.x, fmaf(w1v.y, f.y, fmaf(w1v.z, f.z, fmaf(w1v.w, f.w, acc[1][j]))));
        }
      }
    }
    float add0 = mode ? c1s[hh] : 0.f;
    float add1 = mode ? c1s[hh + 16] : 0.f;
    float* ob = outw + ((size_t)b * NKV + m0) * Hh;
#pragma unroll
    for (int j = 0; j < 4; ++j) {
      ob[(rr + j * 16) * Hh + hh] = acc[0][j] + add0;
      ob[(rr + j * 16) * Hh + hh + 16] = acc[1][j] + add1;
    }
  }
}

// ------------- kernel 2 (fused tail): merge tree -> gather+maxpool -> matvec+BN2+leaky -------------
// [r4/r8-verified at 275.0us total — best measured; r9's 16q variant was neutral-negative,
// reverted] 32 q/block, hoisted qadd load, xs stride 33. r7 lesson: do NOT add work here.
template <int NSLt>
__global__ __launch_bounds__(256, 4) void k_tail(
    const double* __restrict__ pd, const char* __restrict__ ws_c,
    float* __restrict__ out) {
  __shared__ double mg[32][NSLt / 2][17];                 // 17.4 KB (NSL=8)
  __shared__ double mg2[(NSLt == 8) ? 32 : 1][2][17];     // 8.7 KB
  __shared__ int sidx[32 * 17];                           // 2.2 KB
  __shared__ float xs[Hh * 33];                           // 4.2 KB, xs[h][q] stride 33
  int t = threadIdx.x;
  int b = blockIdx.y, q0 = blockIdx.x * 32;

  // hoisted phase-2 operand (independent of phase 1)
  int q2 = t >> 3, l2 = t & 7;
  const float4* qa = (const float4*)(ws_c + OFF_QADD) + ((size_t)b * NQ + q0 + q2) * 8 + l2;
  float4 av = *qa;

  const double* base = pd + ((size_t)b * NQ + q0) * NSLt * KNN;
  double b0, b1, b2, b3, b4, b5, b6, b7, b8, b9, b10, b11, b12, b13, b14, b15;
  double c0, c1, c2, c3, c4, c5, c6, c7, c8, c9, c10, c11, c12, c13, c14, c15;

  if constexpr (NSLt == 8) {
    if (t < 128) {  // level 1: 4 thr/q, thread p merges lists (2p, 2p+1) — contiguous 256 B
      int q = t >> 2, p = t & 3;
      const double* L = base + ((size_t)q * NSLt + 2 * p) * KNN;
      LOADB16(L)
      LOADC16(L + 16)
      MERGE16
      STOREB16(&mg[q][p][0])
    }
    __syncthreads();
    if (t < 64) {  // level 2
      int q = t >> 1, p = t & 1;
      LOADB16(&mg[q][2 * p][0])
      LOADC16(&mg[q][2 * p + 1][0])
      MERGE16
      STOREB16(&mg2[q][p][0])
    }
    __syncthreads();
  } else {  // NSLt == 4
    if (t < 64) {
      int q = t >> 1, p = t & 1;
      const double* L = base + ((size_t)q * NSLt + 2 * p) * KNN;
      LOADB16(L)
      LOADC16(L + 16)
      MERGE16
      STOREB16(&mg[q][p][0])
    }
    __syncthreads();
  }
  if (t < 32) {  // final level -> sidx (OR-packed keys: idx = low 12 mantissa bits)
    if constexpr (NSLt == 8) {
      LOADB16(&mg2[t][0][0])
      LOADC16(&mg2[t][1][0])
    } else {
      LOADB16(&mg[t][0][0])
      LOADC16(&mg[t][1][0])
    }
    MERGE16
    int* si = &sidx[t * 17];
    si[0] = (int)(__double_as_longlong(b0) & 4095);
    si[1] = (int)(__double_as_longlong(b1) & 4095);
    si[2] = (int)(__double_as_longlong(b2) & 4095);
    si[3] = (int)(__double_as_longlong(b3) & 4095);
    si[4] = (int)(__double_as_longlong(b4) & 4095);
    si[5] = (int)(__double_as_longlong(b5) & 4095);
    si[6] = (int)(__double_as_longlong(b6) & 4095);
    si[7] = (int)(__double_as_longlong(b7) & 4095);
    si[8] = (int)(__double_as_longlong(b8) & 4095);
    si[9] = (int)(__double_as_longlong(b9) & 4095);
    si[10] = (int)(__double_as_longlong(b10) & 4095);
    si[11] = (int)(__double_as_longlong(b11) & 4095);
    si[12] = (int)(__double_as_longlong(b12) & 4095);
    si[13] = (int)(__double_as_longlong(b13) & 4095);
    si[14] = (int)(__double_as_longlong(b14) & 4095);
    si[15] = (int)(__double_as_longlong(b15) & 4095);
  }
  __syncthreads();
  // ---- phase 2: gather + maxpool + qadd + leaky -> xs (transposed, stride 33) ----
  {
    const float4* kvs = (const float4*)(ws_c + OFF_KVS) + (size_t)b * NKV * 8 + l2;
    float4 p0 = make_float4(-3.4e38f, -3.4e38f, -3.4e38f, -3.4e38f);
#pragma unroll
    for (int n = 0; n < KNN; ++n) {
      int m = sidx[q2 * 17 + n];
      float4 v0 = kvs[(size_t)m * 8];
      p0.x = fmaxf(p0.x, v0.x); p0.y = fmaxf(p0.y, v0.y);
      p0.z = fmaxf(p0.z, v0.z); p0.w = fmaxf(p0.w, v0.w);
    }
    int h0 = 4 * l2;
    xs[(h0 + 0) * 33 + q2] = leaky(p0.x + av.x);
    xs[(h0 + 1) * 33 + q2] = leaky(p0.y + av.y);
    xs[(h0 + 2) * 33 + q2] = leaky(p0.z + av.z);
    xs[(h0 + 3) * 33 + q2] = leaky(p0.w + av.w);
  }
  __syncthreads();
  // ---- phase 3: y = leaky(w2t · x + b2f) ----
  {
    int ql = t & 31, cb = t >> 5;  // cb half-wave-uniform -> w2t loads L1-broadcast
    const float* w2t = (const float*)(ws_c + OFF_W2T);
    const float* b2f = (const float*)(ws_c + OFF_B2F);
    float xv[Hh];
#pragma unroll
    for (int h = 0; h < Hh; ++h) xv[h] = xs[h * 33 + ql];
    float4 acc[8];
#pragma unroll
    for (int c4 = 0; c4 < 8; ++c4) acc[c4] = make_float4(0.f, 0.f, 0.f, 0.f);
#pragma unroll
    for (int h = 0; h < Hh; ++h) {
      float xh = xv[h];
      const float4* wrow = (const float4*)(w2t + (size_t)h * Cc + cb * 32);
#pragma unroll
      for (int c4 = 0; c4 < 8; ++c4) {
        float4 w = wrow[c4];
        acc[c4].x = fmaf(xh, w.x, acc[c4].x);
        acc[c4].y = fmaf(xh, w.y, acc[c4].y);
        acc[c4].z = fmaf(xh, w.z, acc[c4].z);
        acc[c4].w = fmaf(xh, w.w, acc[c4].w);
      }
    }
    float* o = out + ((size_t)b * NQ + q0 + ql) * Cc + cb * 32;
    const float4* bb = (const float4*)(b2f + cb * 32);
#pragma unroll
    for (int c4 = 0; c4 < 8; ++c4) {
      float4 bv = bb[c4];
      float4 r;
      r.x = leaky(acc[c4].x + bv.x); r.y = leaky(acc[c4].y + bv.y);
      r.z = leaky(acc[c4].z + bv.z); r.w = leaky(acc[c4].w + bv.w);
      *(float4*)(o + c4 * 4) = r;
    }
  }
}

extern "C" void kernel_launch(void* const* d_in, const int* in_sizes, int n_in,
                              void* d_out, int out_size, void* d_ws, size_t ws_size,
                              hipStream_t stream) {
  const float* qf   = (const float*)d_in[0];
  const float* qxyz = (const float*)d_in[1];
  const float* kvf  = (const float*)d_in[2];
  const float* kxyz = (const float*)d_in[3];
  const float* w1 = (const float*)d_in[4];
  const float* g1 = (const float*)d_in[5];
  const float* b1 = (const float*)d_in[6];
  const float* m1 = (const float*)d_in[7];
  const float* v1 = (const float*)d_in[8];
  const float* w2 = (const float*)d_in[9];
  const float* g2 = (const float*)d_in[10];
  const float* b2 = (const float*)d_in[11];
  const float* m2 = (const float*)d_in[12];
  const float* v2 = (const float*)d_in[13];
  char* ws = (char*)d_ws;
  double* pd = (double*)(ws + OFF_PD);

  // NSL=8 needs OFF_PD + 8*4096*8*16*8 ~= 42 MB of ws; fall back to NSL=4 otherwise.
  size_t need8 = (size_t)OFF_PD + (size_t)Bz * NQ * 8 * KNN * sizeof(double);
  if (ws_size >= need8) {
    k_sf<512><<<dim3(1024), dim3(256), 0, stream>>>(
        qxyz, kxyz, kvf, qf, w1, g1, b1, m1, v1, w2, g2, b2, m2, v2, ws, pd);
    k_tail<8><<<dim3(NQ / 32, Bz), 256, 0, stream>>>(pd, ws, (float*)d_out);
  } else {
    k_sf<1024><<<dim3(1024), dim3(256), 0, stream>>>(
        qxyz, kxyz, kvf, qf, w1, g1, b1, m1, v1, w2, g2, b2, m2, v2, ws, pd);
    k_tail<4><<<dim3(NQ / 32, Bz), 256, 0, stream>>>(pd, ws, (float*)d_out);
  }
}